// Round 3
// baseline (249.881 us; speedup 1.0000x reference)
//
#include <hip/hip_runtime.h>

#define DDIM 256
#define NTOK 4096   // B*S = 64*64
#define NEGN 8192
#define BTM 128     // big-gemm tile M
#define BTN 128     // big-gemm tile N
#define GX  32      // NTOK/BTM x-tiles (hardcoded in swizzle)
// small 64x64 kernel (fr alignment)
#define TM 64
#define TN 64
#define LDT 40      // padded halfs per LDS row for the small kernel

typedef __attribute__((ext_vector_type(8))) short bf16x8;
typedef __attribute__((ext_vector_type(4))) float f32x4;

__device__ inline unsigned short f2bf(float f) {
    unsigned int u = __float_as_uint(f);
    unsigned int r = u + 0x7FFFu + ((u >> 16) & 1u);
    return (unsigned short)(r >> 16);
}

// global->LDS direct DMA, 16B/lane; LDS dest = wave-uniform base + lane*16.
__device__ inline void gl_lds16(const unsigned short* g, unsigned short* l) {
    __builtin_amdgcn_global_load_lds(
        reinterpret_cast<__attribute__((address_space(1))) unsigned int*>(
            reinterpret_cast<uintptr_t>(g)),
        reinterpret_cast<__attribute__((address_space(3))) unsigned int*>(
            reinterpret_cast<uintptr_t>(l)),
        16, 0, 0);
}

// DPP 16-lane sum reduction (quad xor1, xor2, half-mirror, mirror) — VALU only.
template<int CTRL>
__device__ inline float dpp_add(float x) {
    int v = __builtin_amdgcn_update_dpp(0, __float_as_int(x), CTRL, 0xF, 0xF, false);
    return x + __int_as_float(v);
}
__device__ inline float red16(float x) {
    x = dpp_add<0xB1>(x);    // quad_perm [1,0,3,2]
    x = dpp_add<0x4E>(x);    // quad_perm [2,3,0,1]
    x = dpp_add<0x141>(x);   // row_half_mirror
    x = dpp_add<0x140>(x);   // row_mirror
    return x;
}

// ---------------------------------------------------------------------------
// Kernel 1: gather + fp32->bf16 convert + fused en_score.
// Row space: z | E_en | E_fr | be_fr | en_score-rows.
// ---------------------------------------------------------------------------
__global__ void gather_kernel(
    const float* __restrict__ zs,
    const float* __restrict__ W_en, const float* __restrict__ W_fr,
    const int* __restrict__ pos_en, const int* __restrict__ neg_en,
    const int* __restrict__ pos_fr, const int* __restrict__ neg_fr,
    const int* __restrict__ x_fr, const int* __restrict__ x_en,
    const float* __restrict__ kappa_en, const float* __restrict__ kappa_fr,
    unsigned short* __restrict__ z_bf,
    unsigned short* __restrict__ E_en, unsigned short* __restrict__ E_fr,
    unsigned short* __restrict__ be_fr,
    float* __restrict__ w_en, float* __restrict__ w_fr,
    float* __restrict__ en_score,
    int Pe, int Pf, int Lpe, int Lpf)
{
    int row  = blockIdx.x * 4 + (threadIdx.x >> 6);
    int lane = threadIdx.x & 63;
    const float* src = nullptr;
    unsigned short* dst = nullptr;
    bool zero = false;

    if (row < NTOK) {
        src = zs + (size_t)row * DDIM;
        dst = z_bf + (size_t)row * DDIM;
    } else if (row < NTOK + Lpe) {
        int j = row - NTOK;
        int Le = Pe + NEGN;
        int idx = 0;
        if (j < Pe)      idx = pos_en[j];
        else if (j < Le) idx = neg_en[j - Pe];
        else             zero = true;
        src = W_en + (size_t)idx * DDIM;
        dst = E_en + (size_t)j * DDIM;
        if (lane == 0) w_en[j] = (j < Pe) ? 1.0f : (j < Le ? kappa_en[0] : 0.0f);
    } else if (row < NTOK + Lpe + Lpf) {
        int j = row - NTOK - Lpe;
        int Lf = Pf + NEGN;
        int idx = 0;
        if (j < Pf)      idx = pos_fr[j];
        else if (j < Lf) idx = neg_fr[j - Pf];
        else             zero = true;
        src = W_fr + (size_t)idx * DDIM;
        dst = E_fr + (size_t)j * DDIM;
        if (lane == 0) w_fr[j] = (j < Pf) ? 1.0f : (j < Lf ? kappa_fr[0] : 0.0f);
    } else if (row < NTOK + Lpe + Lpf + NTOK) {
        int j = row - NTOK - Lpe - Lpf;
        int idx = x_fr[j];
        src = W_fr + (size_t)idx * DDIM;
        dst = be_fr + (size_t)j * DDIM;
    } else if (row < NTOK + Lpe + Lpf + NTOK + NTOK) {
        // fused en_score: zs[j] . W_en[x_en[j]] in fp32, wave reduce
        int j = row - NTOK - Lpe - Lpf - NTOK;
        int idx = x_en[j];
        float4 z = *(const float4*)(zs   + (size_t)j   * DDIM + lane * 4);
        float4 w = *(const float4*)(W_en + (size_t)idx * DDIM + lane * 4);
        float s = z.x * w.x + z.y * w.y + z.z * w.z + z.w * w.w;
        #pragma unroll
        for (int m = 32; m; m >>= 1) s += __shfl_xor(s, m);
        if (lane == 0) en_score[j] = s;
        return;
    } else {
        return;
    }

    int d = lane * 4;
    float4 v;
    if (zero) { v.x = v.y = v.z = v.w = 0.0f; }
    else      { v = *(const float4*)(src + d); }
    ushort4 o;
    o.x = f2bf(v.x); o.y = f2bf(v.y); o.z = f2bf(v.z); o.w = f2bf(v.w);
    *(ushort4*)(dst + d) = o;
}

// ---------------------------------------------------------------------------
// Kernel 2: fused denominators. 128x128 tile, double-buffered LDS,
// chunk-major (lane-major) sub-tile layout -> conflict-free ds_read_b128,
// DPP epilogue reduction, XCD-aware y swizzle.
// LDS layout: sub-tile s (16 rows) at s*1KB; element (row b, chunk q) at
// q*256B + b*16B  == lane-major (DMA writes lane L at L*16B).
// Frag read: row m=16s+col chunk quad -> s*512 + quad*128 + col*8 (halfs).
// ---------------------------------------------------------------------------
__global__ __launch_bounds__(256) void expsum_gemm128(
    const unsigned short* __restrict__ A,   // [4096 x 256] bf16 (z)
    const unsigned short* __restrict__ E,   // [(Lpe+Lpf) x 256] bf16
    const float* __restrict__ wts,          // [Lpe+Lpf]
    float* __restrict__ out_en, float* __restrict__ out_fr,
    int ysplit, int Lpe, int nytiles)
{
    __shared__ __align__(16) unsigned short As[2][BTM * 32];
    __shared__ __align__(16) unsigned short Bs[2][BTN * 32];

    // XCD-aware swizzle: each XCD (linid%8) owns y-tiles {xcd, xcd+8, ...}
    int lin  = blockIdx.y * GX + blockIdx.x;
    int xcd  = lin & 7;
    int rest = lin >> 3;
    int xb   = rest & 31;          // GX = 32
    int yb   = xcd + 8 * (rest >> 5);
    if (yb >= nytiles) return;

    int t    = threadIdx.x;
    int lane = t & 63;
    int wave = t >> 6;
    int col  = lane & 15;
    int quad = lane >> 4;
    int wm   = wave & 1;
    int wn   = wave >> 1;

    const unsigned short* Bb;
    float* out;
    int nbase;
    if (yb < ysplit) {
        Bb = E + (size_t)yb * BTN * DDIM;
        out = out_en; nbase = yb * BTN;
    } else {
        Bb = E + ((size_t)Lpe + (size_t)(yb - ysplit) * BTN) * DDIM;
        out = out_fr; nbase = Lpe + (yb - ysplit) * BTN;
    }
    const unsigned short* Ab = A + (size_t)xb * BTM * DDIM;

    // staging: wave w stages sub-tiles {2w, 2w+1} of A and B.
    // lane L sources global (row = 16*subtile + (L&15), chunk = L>>4).
    int b = col, q = quad;
    const unsigned short* gA0 = Ab + (size_t)(32 * wave + b) * DDIM + q * 8;
    const unsigned short* gA1 = gA0 + 16 * DDIM;
    const unsigned short* gB0 = Bb + (size_t)(32 * wave + b) * DDIM + q * 8;
    const unsigned short* gB1 = gB0 + 16 * DDIM;
    int ldsbase = wave * 1024;     // halfs: sub-tile 2w at 2w*512

    f32x4 acc[4][4];
    #pragma unroll
    for (int i = 0; i < 4; i++)
        #pragma unroll
        for (int j = 0; j < 4; j++)
            acc[i][j] = (f32x4){0.f, 0.f, 0.f, 0.f};

    // prefetch k-tile 0 into buffer 0
    gl_lds16(gA0, &As[0][ldsbase]);
    gl_lds16(gA1, &As[0][ldsbase + 512]);
    gl_lds16(gB0, &Bs[0][ldsbase]);
    gl_lds16(gB1, &Bs[0][ldsbase + 512]);

    for (int k8 = 0; k8 < 8; k8++) {
        int cur = k8 & 1, nxt = cur ^ 1;
        __syncthreads();            // drains cur's DMA; nxt's readers done
        if (k8 < 7) {
            int kk = (k8 + 1) * 32;
            gl_lds16(gA0 + kk, &As[nxt][ldsbase]);
            gl_lds16(gA1 + kk, &As[nxt][ldsbase + 512]);
            gl_lds16(gB0 + kk, &Bs[nxt][ldsbase]);
            gl_lds16(gB1 + kk, &Bs[nxt][ldsbase + 512]);
        }
        bf16x8 af[4], bfv[4];
        #pragma unroll
        for (int i = 0; i < 4; i++)
            af[i] = *(const bf16x8*)(&As[cur][(wm * 4 + i) * 512 + quad * 128 + col * 8]);
        #pragma unroll
        for (int j = 0; j < 4; j++)
            bfv[j] = *(const bf16x8*)(&Bs[cur][(wn * 4 + j) * 512 + quad * 128 + col * 8]);
        #pragma unroll
        for (int i = 0; i < 4; i++)
            #pragma unroll
            for (int j = 0; j < 4; j++)
                acc[i][j] = __builtin_amdgcn_mfma_f32_16x16x32_bf16(af[i], bfv[j], acc[i][j], 0, 0, 0);
    }

    // epilogue: weighted exp, DPP-reduce over 16 cols (n), atomic accumulate
    float wj[4];
    #pragma unroll
    for (int j = 0; j < 4; j++)
        wj[j] = wts[nbase + wn * 64 + 16 * j + col];

    #pragma unroll
    for (int i = 0; i < 4; i++) {
        #pragma unroll
        for (int r = 0; r < 4; r++) {
            float s = wj[0] * __expf(acc[i][0][r]) + wj[1] * __expf(acc[i][1][r])
                    + wj[2] * __expf(acc[i][2][r]) + wj[3] * __expf(acc[i][3][r]);
            s = red16(s);
            if (col == 0)
                atomicAdd(out + xb * BTM + wm * 64 + 16 * i + quad * 4 + r, s);
        }
    }
}

// ---------------------------------------------------------------------------
// Kernel 3: fr alignment (per-batch 64x64 exp-sum, weight 1/denom_fr) with
// the final loss reduction fused in (reads en_score/denom_en too).
// ---------------------------------------------------------------------------
__global__ __launch_bounds__(256) void expsum_gemm64_loss(
    const unsigned short* __restrict__ A,   // be_fr [B][64 x 256]
    const unsigned short* __restrict__ Bm,  // z_bf  [B][64 x 256]
    const float* __restrict__ denom_fr,     // [B*64]
    const float* __restrict__ denom_en,     // [B*64]
    const float* __restrict__ en_score,     // [B*64]
    const float* __restrict__ en_mask,
    const float* __restrict__ fr_mask,
    float* __restrict__ outloss)            // [128]: en | fr
{
    __shared__ __align__(16) unsigned short lda[TM * LDT];
    __shared__ __align__(16) unsigned short ldb[TN * LDT];
    __shared__ float tbuf[64];

    int batch = blockIdx.x;
    const unsigned short* Ab = A  + (size_t)batch * TM * DDIM;
    const unsigned short* Bb = Bm + (size_t)batch * TN * DDIM;

    int t      = threadIdx.x;
    int srow   = t >> 2;
    int schunk = t & 3;
    int lane   = t & 63;
    int wave   = t >> 6;
    int col    = lane & 15;
    int quad   = lane >> 4;

    f32x4 acc0 = {0.f,0.f,0.f,0.f};
    f32x4 acc1 = {0.f,0.f,0.f,0.f};
    f32x4 acc2 = {0.f,0.f,0.f,0.f};
    f32x4 acc3 = {0.f,0.f,0.f,0.f};

    for (int kk = 0; kk < DDIM; kk += 32) {
        uint4 av = *(const uint4*)(Ab + (size_t)srow * DDIM + kk + schunk * 8);
        uint4 bv = *(const uint4*)(Bb + (size_t)srow * DDIM + kk + schunk * 8);
        __syncthreads();
        *(uint4*)(lda + srow * LDT + schunk * 8) = av;
        *(uint4*)(ldb + srow * LDT + schunk * 8) = bv;
        __syncthreads();

        bf16x8 af = *(const bf16x8*)(lda + (wave * 16 + col) * LDT + quad * 8);
        bf16x8 b0 = *(const bf16x8*)(ldb + ( 0 + col) * LDT + quad * 8);
        bf16x8 b1 = *(const bf16x8*)(ldb + (16 + col) * LDT + quad * 8);
        bf16x8 b2 = *(const bf16x8*)(ldb + (32 + col) * LDT + quad * 8);
        bf16x8 b3 = *(const bf16x8*)(ldb + (48 + col) * LDT + quad * 8);
        acc0 = __builtin_amdgcn_mfma_f32_16x16x32_bf16(af, b0, acc0, 0, 0, 0);
        acc1 = __builtin_amdgcn_mfma_f32_16x16x32_bf16(af, b1, acc1, 0, 0, 0);
        acc2 = __builtin_amdgcn_mfma_f32_16x16x32_bf16(af, b2, acc2, 0, 0, 0);
        acc3 = __builtin_amdgcn_mfma_f32_16x16x32_bf16(af, b3, acc3, 0, 0, 0);
    }

    const float* db = denom_fr + batch * 64;
    float w0 = 1.0f / db[ 0 + col];
    float w1 = 1.0f / db[16 + col];
    float w2 = 1.0f / db[32 + col];
    float w3 = 1.0f / db[48 + col];

    float tot0 = w0 * __expf(acc0.x) + w1 * __expf(acc1.x) + w2 * __expf(acc2.x) + w3 * __expf(acc3.x);
    float tot1 = w0 * __expf(acc0.y) + w1 * __expf(acc1.y) + w2 * __expf(acc2.y) + w3 * __expf(acc3.y);
    float tot2 = w0 * __expf(acc0.z) + w1 * __expf(acc1.z) + w2 * __expf(acc2.z) + w3 * __expf(acc3.z);
    float tot3 = w0 * __expf(acc0.w) + w1 * __expf(acc1.w) + w2 * __expf(acc2.w) + w3 * __expf(acc3.w);

    #pragma unroll
    for (int m = 1; m < 16; m <<= 1) {
        tot0 += __shfl_xor(tot0, m);
        tot1 += __shfl_xor(tot1, m);
        tot2 += __shfl_xor(tot2, m);
        tot3 += __shfl_xor(tot3, m);
    }
    if (col == 0) {
        int base = wave * 16 + quad * 4;
        tbuf[base + 0] = tot0; tbuf[base + 1] = tot1;
        tbuf[base + 2] = tot2; tbuf[base + 3] = tot3;
    }
    __syncthreads();

    // fused loss: one wave finishes batch b
    if (t < 64) {
        int i = batch * 64 + t;
        float a = (en_score[i] - __logf(denom_en[i])) * en_mask[i];
        float c = __logf(tbuf[t]) * fr_mask[i];
        #pragma unroll
        for (int m = 32; m; m >>= 1) { a += __shfl_xor(a, m); c += __shfl_xor(c, m); }
        if (t == 0) { outloss[batch] = a; outloss[64 + batch] = c; }
    }
}

extern "C" void kernel_launch(void* const* d_in, const int* in_sizes, int n_in,
                              void* d_out, int out_size, void* d_ws, size_t ws_size,
                              hipStream_t stream)
{
    const float* zs       = (const float*)d_in[0];
    const int*   x_en     = (const int*)d_in[1];
    const int*   x_fr     = (const int*)d_in[2];
    const float* en_mask  = (const float*)d_in[3];
    const float* fr_mask  = (const float*)d_in[4];
    const float* W_en     = (const float*)d_in[5];
    const float* W_fr     = (const float*)d_in[6];
    const int*   pos_en   = (const int*)d_in[7];
    const int*   neg_en   = (const int*)d_in[8];
    const int*   pos_fr   = (const int*)d_in[9];
    const int*   neg_fr   = (const int*)d_in[10];
    const float* kappa_en = (const float*)d_in[11];
    const float* kappa_fr = (const float*)d_in[12];

    int Pe  = in_sizes[7];
    int Pf  = in_sizes[9];
    int Lpe = (Pe + NEGN + 127) & ~127;   // 128-aligned for BTN tiles
    int Lpf = (Pf + NEGN + 127) & ~127;

    char* w = (char*)d_ws;
    float* denom_en = (float*)w; w += NTOK * 4;
    float* denom_fr = (float*)w; w += NTOK * 4;
    float* en_score = (float*)w; w += NTOK * 4;
    float* w_all    = (float*)w; w += (size_t)(Lpe + Lpf) * 4;
    unsigned short* z_bf  = (unsigned short*)w; w += (size_t)NTOK * DDIM * 2;
    unsigned short* E_all = (unsigned short*)w; w += (size_t)(Lpe + Lpf) * DDIM * 2;
    unsigned short* be_fr = (unsigned short*)w; w += (size_t)NTOK * DDIM * 2;

    // zero the atomic accumulators (denom_en, denom_fr adjacent)
    hipMemsetAsync(denom_en, 0, (size_t)NTOK * 2 * 4, stream);

    int totrows = NTOK + Lpe + Lpf + NTOK + NTOK;
    gather_kernel<<<(totrows + 3) / 4, 256, 0, stream>>>(
        zs, W_en, W_fr, pos_en, neg_en, pos_fr, neg_fr, x_fr, x_en,
        kappa_en, kappa_fr, z_bf, E_all, E_all + (size_t)Lpe * DDIM, be_fr,
        w_all, w_all + Lpe, en_score, Pe, Pf, Lpe, Lpf);

    // fused denominators; gridY padded to multiple of 8 for the XCD swizzle
    int NE = Lpe / BTN, NF = Lpf / BTN;
    int NY = NE + NF;
    int NYP = (NY + 7) & ~7;
    expsum_gemm128<<<dim3(GX, NYP, 1), 256, 0, stream>>>(
        z_bf, E_all, w_all, denom_en, denom_fr, NE, Lpe, NY);

    // fr alignment + fused loss
    expsum_gemm64_loss<<<64, 256, 0, stream>>>(
        be_fr, z_bf, denom_fr, denom_en, en_score, en_mask, fr_mask,
        (float*)d_out);
}